// Round 10
// baseline (428.307 us; speedup 1.0000x reference)
//
#include <hip/hip_runtime.h>
#include <hip/hip_bf16.h>
#include <math.h>

// Problem dims (fixed by reference setup_inputs)
#define D_IN   1024
#define D_HID  4096
#define M_TOK  16384   // 4 * 4096 tokens

typedef int v4i __attribute__((ext_vector_type(4)));
typedef _Float16 f16x8 __attribute__((ext_vector_type(8)));

typedef __attribute__((address_space(3))) unsigned int lds_u32;
typedef const __attribute__((address_space(1))) unsigned int glb_u32;

// async global->LDS, 16B per lane, wave-uniform LDS base + lane*16
__device__ inline void gload_lds16(const signed char* g, signed char* l) {
    __builtin_amdgcn_global_load_lds((glb_u32*)g, (lds_u32*)l, 16, 0, 0);
}

// Branchless erf, Abramowitz-Stegun 7.1.26, |eps| <= 1.5e-7 (<< fp16-h rounding).
__device__ inline float fast_erf(float x) {
    float ax = fabsf(x);
    float t = __builtin_amdgcn_rcpf(fmaf(0.3275911f, ax, 1.0f));
    float y = t * (0.254829592f +
              t * (-0.284496736f +
              t * (1.421413741f +
              t * (-1.453152027f +
              t * 1.061405429f))));
    float e = __expf(-ax * ax);          // native v_exp path
    float r = fmaf(-y, e, 1.0f);
    return copysignf(r, x);
}

// ---------------- workspace layout (bytes) ----------------
#define OFF_SLOTS  ((size_t)0)                                   // 8 x u32 atomic slots
#define OFF_SCAL   ((size_t)64)                                  // 16 x f32 scalars
#define OFF_ISCAL  ((size_t)128)                                 // 8 x i32
#define OFF_XQ     ((size_t)256)                                 // 16M  int8
#define OFF_W1Q    (OFF_XQ  + (size_t)M_TOK * D_IN)              // 4M   int8
#define OFF_W2Q    (OFF_W1Q + (size_t)D_HID * D_IN)              // 4M   int8
#define OFF_RS1    (OFF_W2Q + (size_t)D_IN * D_HID)              // 16K  i32
#define OFF_RS2    (OFF_RS1 + (size_t)D_HID * 4)                 // 4K   i32
#define OFF_H      (OFF_RS2 + (size_t)D_IN * 4 + 128)            // 128M fp16
#define OFF_PART   (OFF_H   + (size_t)M_TOK * D_HID * 2)         // 10K  f32 partials
// hq workspace eliminated (R10): gemm2 quantizes H in-register during staging.
// Partials (k_reduce_all -> k_quant_all) live after H; never overwritten.

// slots: [4] h min(enc) [5] h max(enc)
// scal:  [0] sx1 [1] zx1f [2] sw1 [3] sw2 [4] s1=sx1*sw1   (written by quant_all blk 0)
// iscal: [0] zx1

__device__ inline unsigned enc_f(float f) {
    unsigned u = __float_as_uint(f);
    return (u & 0x80000000u) ? ~u : (u | 0x80000000u);
}
__device__ inline float dec_f(unsigned u) {
    return __uint_as_float((u & 0x80000000u) ? (u ^ 0x80000000u) : ~u);
}

// ---- fused stage-1 reductions: x min/max + |W1|max + |W2|max, deterministic partials
__global__ void k_reduce_all(const float4* __restrict__ x,
                             const float4* __restrict__ w1,
                             const float4* __restrict__ w2,
                             float* __restrict__ pxmin, float* __restrict__ pxmax,
                             float* __restrict__ pw1, float* __restrict__ pw2) {
    __shared__ float red[8];
    const int b = blockIdx.x;
    const int wave = threadIdx.x >> 6, lane = threadIdx.x & 63;
    if (b < 1024) {
        float vmin = 3.4e38f, vmax = -3.4e38f;
        for (int i = b * 256 + threadIdx.x; i < M_TOK * D_IN / 4; i += 1024 * 256) {
            float4 v = x[i];
            vmin = fminf(vmin, fminf(fminf(v.x, v.y), fminf(v.z, v.w)));
            vmax = fmaxf(vmax, fmaxf(fmaxf(v.x, v.y), fmaxf(v.z, v.w)));
        }
        for (int off = 32; off > 0; off >>= 1) {
            vmin = fminf(vmin, __shfl_down(vmin, off));
            vmax = fmaxf(vmax, __shfl_down(vmax, off));
        }
        if (lane == 0) { red[wave] = vmin; red[4 + wave] = vmax; }
        __syncthreads();
        if (threadIdx.x == 0) {
            pxmin[b] = fminf(fminf(red[0], red[1]), fminf(red[2], red[3]));
            pxmax[b] = fmaxf(fmaxf(red[4], red[5]), fmaxf(red[6], red[7]));
        }
    } else {
        const float4* w = (b < 1280) ? w1 : w2;
        const int bb = (b < 1280) ? b - 1024 : b - 1280;
        float vmax = 0.0f;
        for (int i = bb * 256 + threadIdx.x; i < D_HID * D_IN / 4; i += 256 * 256) {
            float4 v = w[i];
            vmax = fmaxf(vmax, fmaxf(fmaxf(fabsf(v.x), fabsf(v.y)), fmaxf(fabsf(v.z), fabsf(v.w))));
        }
        for (int off = 32; off > 0; off >>= 1)
            vmax = fmaxf(vmax, __shfl_down(vmax, off));
        if (lane == 0) red[wave] = vmax;
        __syncthreads();
        if (threadIdx.x == 0) {
            float bm = fmaxf(fmaxf(red[0], red[1]), fmaxf(red[2], red[3]));
            if (b < 1280) pw1[bb] = bm; else pw2[bb] = bm;
        }
    }
}

// ---- fused stage-1 quantization (scales folded in):
// x (blocks 0..2047), W1 rows (2048..6143), W2 rows (6144..7167).
__global__ void k_quant_all(const float4* __restrict__ x, int* __restrict__ xq,
                            const float* __restrict__ W1, signed char* __restrict__ w1q,
                            int* __restrict__ rs1,
                            const float* __restrict__ W2, signed char* __restrict__ w2q,
                            int* __restrict__ rs2,
                            const float* __restrict__ pxmin, const float* __restrict__ pxmax,
                            const float* __restrict__ pw1, const float* __restrict__ pw2,
                            float* __restrict__ scal, int* __restrict__ iscal,
                            unsigned* __restrict__ slots) {
    __shared__ float sred[8];
    __shared__ int red[4];
    const int b = blockIdx.x;
    const int wave = threadIdx.x >> 6, lane = threadIdx.x & 63;

    if (b < 2048) {
        float vmin = 3.4e38f, vmax = -3.4e38f;
        for (int i = threadIdx.x; i < 1024; i += 256) {
            vmin = fminf(vmin, pxmin[i]);
            vmax = fmaxf(vmax, pxmax[i]);
        }
        for (int off = 32; off > 0; off >>= 1) {
            vmin = fminf(vmin, __shfl_down(vmin, off));
            vmax = fmaxf(vmax, __shfl_down(vmax, off));
        }
        if (lane == 0) { sred[wave] = vmin; sred[4 + wave] = vmax; }
        __syncthreads();
        vmin = fminf(fminf(sred[0], sred[1]), fminf(sred[2], sred[3]));
        vmax = fmaxf(fmaxf(sred[4], sred[5]), fmaxf(sred[6], sred[7]));
        float s = fmaxf((vmax - vmin) / 255.0f, 1e-8f);
        float zp = rintf(-vmin / s) - 128.0f;
        zp = fminf(fmaxf(zp, -128.0f), 127.0f);

        if (b == 0 && threadIdx.x == 0) {
            float w1m = 0.0f, w2m = 0.0f;
            for (int i = 0; i < 256; i++) {
                w1m = fmaxf(w1m, pw1[i]);
                w2m = fmaxf(w2m, pw2[i]);
            }
            float sw1 = fmaxf(w1m / 127.0f, 1e-8f);
            float sw2 = fmaxf(w2m / 127.0f, 1e-8f);
            scal[0] = s; scal[1] = zp; scal[2] = sw1; scal[3] = sw2; scal[4] = s * sw1;
            iscal[0] = (int)zp;
            slots[4] = 0xFFFFFFFFu;   // h min (enc)
            slots[5] = 0u;            // h max (enc)
        }

        for (int i = b * 256 + threadIdx.x; i < M_TOK * D_IN / 4; i += 2048 * 256) {
            float4 v = x[i];
            int a0 = (int)fminf(fmaxf(rintf(v.x / s) + zp, -128.0f), 127.0f);
            int a1 = (int)fminf(fmaxf(rintf(v.y / s) + zp, -128.0f), 127.0f);
            int a2 = (int)fminf(fmaxf(rintf(v.z / s) + zp, -128.0f), 127.0f);
            int a3 = (int)fminf(fmaxf(rintf(v.w / s) + zp, -128.0f), 127.0f);
            xq[i] = (a0 & 255) | ((a1 & 255) << 8) | ((a2 & 255) << 16) | ((a3 & 255) << 24);
        }
        return;
    }

    const int isW1 = (b < 2048 + 4096);
    const int row = isW1 ? (b - 2048) : (b - 6144);
    const int K = isW1 ? D_IN : D_HID;
    const float* pw = isW1 ? pw1 : pw2;
    const float* W = isW1 ? W1 : W2;
    signed char* Wq = isW1 ? w1q : w2q;
    int* rsum = isW1 ? rs1 : rs2;

    float wm = pw[threadIdx.x & 255];
    for (int off = 32; off > 0; off >>= 1)
        wm = fmaxf(wm, __shfl_down(wm, off));
    if (lane == 0) sred[wave] = wm;
    __syncthreads();
    wm = fmaxf(fmaxf(sred[0], sred[1]), fmaxf(sred[2], sred[3]));
    const float s = fmaxf(wm / 127.0f, 1e-8f);

    const float4* Wr = (const float4*)(W + (size_t)row * K);
    int* out = (int*)(Wq + (size_t)row * K);
    int mysum = 0;
    for (int i = threadIdx.x; i < K / 4; i += 256) {
        float4 v = Wr[i];
        int a0 = (int)fminf(fmaxf(rintf(v.x / s), -127.0f), 127.0f);
        int a1 = (int)fminf(fmaxf(rintf(v.y / s), -127.0f), 127.0f);
        int a2 = (int)fminf(fmaxf(rintf(v.z / s), -127.0f), 127.0f);
        int a3 = (int)fminf(fmaxf(rintf(v.w / s), -127.0f), 127.0f);
        mysum += a0 + a1 + a2 + a3;
        out[i] = (a0 & 255) | ((a1 & 255) << 8) | ((a2 & 255) << 16) | ((a3 & 255) << 24);
    }
    for (int off = 32; off > 0; off >>= 1)
        mysum += __shfl_down(mysum, off);
    if (lane == 0) red[wave] = mysum;
    __syncthreads();
    if (threadIdx.x == 0) rsum[row] = red[0] + red[1] + red[2] + red[3];
}

// ---------------- int8 MFMA GEMM mainloop, 256x128 tile (gemm1) ----------------
// R10: trailing barrier REMOVED (1 barrier/tile). Safety: iteration t+1's
// leading vmcnt(6)+s_barrier already guarantees all waves finished compute(t)
// (each wave's ds_reads complete via lgkm before its MFMAs, before barrier
// arrival), and stage() is issued AFTER that barrier — so the old trailing
// barrier protected nothing. Triple-buffer rotation + counted vmcnt(6)
// otherwise identical to the R2/R4-verified structure.
// (Closed levers: 3 blocks/CU spills acc [R6]; intra-block phase split
// regresses at 4 waves [R5]; XCD chunk-swizzle thrashes B in L2 [R8].)
__device__ inline void int8_mainloop256(const signed char* __restrict__ A,
                                        const signed char* __restrict__ B,
                                        int K, int m0, int n0,
                                        signed char* Ls, v4i (&acc)[8][4]) {
    const int tid = threadIdx.x;
    const int l = tid & 63, w = tid >> 6;
    const int lm = l & 15, lq = l >> 4;
    const int wmi = w >> 1, wni = w & 1;

    const int gc16 = ((l & 3) ^ ((l >> 3) & 3)) << 4;   // swizzled global chunk
    const int srow = (w << 4) + (l >> 2);               // rows 0..63 (+q*64)
    const signed char* gA = A + (long)(m0 + srow) * K + gc16;
    const signed char* gB = B + (long)(n0 + srow) * K + gc16;
    const long rstep = (long)K << 6;                    // 64 rows
    signed char* lA = Ls + (w << 10) + (l << 4);
    signed char* lB = Ls + 16384 + (w << 10) + (l << 4);

    const int f16off = (lq ^ ((lm >> 1) & 3)) << 4;
    const int aoff = ((wmi << 7) + lm) * 64 + f16off;
    const int boff = 16384 + ((wni << 6) + lm) * 64 + f16off;

    const int KT = K >> 6;

    auto stage = [&](int bufoff, int kt) {
        const signed char* a = gA + ((long)kt << 6);
        const signed char* b = gB + ((long)kt << 6);
        gload_lds16(a,             lA + bufoff);
        gload_lds16(a + rstep,     lA + bufoff + 4096);
        gload_lds16(a + 2 * rstep, lA + bufoff + 8192);
        gload_lds16(a + 3 * rstep, lA + bufoff + 12288);
        gload_lds16(b,             lB + bufoff);
        gload_lds16(b + rstep,     lB + bufoff + 4096);
    };

    auto compute = [&](int bufoff) {
        v4i av[8], bv[4];
#pragma unroll
        for (int j = 0; j < 4; ++j)
            bv[j] = *(const v4i*)&Ls[bufoff + boff + j * 1024];
#pragma unroll
        for (int i = 0; i < 8; ++i)
            av[i] = *(const v4i*)&Ls[bufoff + aoff + i * 1024];
        __builtin_amdgcn_s_setprio(1);
#pragma unroll
        for (int i = 0; i < 8; ++i)
#pragma unroll
            for (int j = 0; j < 4; ++j)
                acc[i][j] = __builtin_amdgcn_mfma_i32_16x16x64_i8(av[i], bv[j], acc[i][j], 0, 0, 0);
        __builtin_amdgcn_s_setprio(0);
    };

    stage(0, 0);
    stage(24576, 1);

    int b0 = 0, b1 = 24576, b2 = 49152;
    for (int t = 0; t < KT - 2; ++t) {
        asm volatile("s_waitcnt vmcnt(6)\n\ts_barrier" ::: "memory");
        stage(b2, t + 2);
        compute(b0);
        int tmp = b0; b0 = b1; b1 = b2; b2 = tmp;
    }
    asm volatile("s_waitcnt vmcnt(6)\n\ts_barrier" ::: "memory");
    compute(b0);
    asm volatile("s_waitcnt vmcnt(0)\n\ts_barrier" ::: "memory");
    compute(b1);
}

// ---------------- gemm2 mainloop: fp16 A with fused quantization ----------------
// R10 (T14 reg-stage): A = H fp16; per iteration t:
//   1. issue 8 f16x8 A-loads(t+1) -> regs R; 2 B-DMAs(t+1) -> other buf
//   2. compute(buf t)               [loads in flight under the MFMAs]
//   3. vmcnt(0): drain A-loads + B-DMAs (issued one compute-phase earlier)
//   4. quantize R (rint(fma(h,1/sh,zp)), clamp, pack) -> ds_write other buf
//   5. lgkmcnt(0); s_barrier        [the iteration's single barrier]
// Double-buffer safety: step-1/4 writes target buf[(t+1)&1], last READ at
// compute(t-1); those reads completed before t-1's step-5 barrier, which
// every wave passed before issuing step 1. Reader at t+1 sees A via
// lgkm-drained ds_writes + barrier, B via each wave's own vmcnt(0) + barrier.
// Numerics: rint(h*rs+zpf) == rint(h/sh)+zp up to knife-edge reciprocal
// rounding (integer-zp commutes with rne exactly); bounded effect << 0.074
// threshold. LDS layout and chunk swizzle identical to the int8 path (lane
// controls both global src and LDS dst).
__device__ inline void int8_mainloop_h(const _Float16* __restrict__ Hm,
                                       const signed char* __restrict__ B,
                                       int K, int m0, int n0,
                                       float rs, float zpf,
                                       signed char* Ls, v4i (&acc)[8][4]) {
    const int tid = threadIdx.x;
    const int l = tid & 63, w = tid >> 6;
    const int lm = l & 15, lq = l >> 4;
    const int wmi = w >> 1, wni = w & 1;

    const int col0 = (l & 3) ^ ((l >> 3) & 3);          // swizzled 16-elem chunk
    const int srow = (w << 4) + (l >> 2);
    const _Float16* gA = Hm + (long)(m0 + srow) * K + col0 * 16;   // elements
    const signed char* gB = B + (long)(n0 + srow) * K + (col0 << 4);
    const long rstep = (long)K << 6;                    // 64 rows (elems==bytes)
    signed char* lA = Ls + (w << 10) + (l << 4);
    signed char* lB = Ls + 16384 + (w << 10) + (l << 4);

    const int f16off = (lq ^ ((lm >> 1) & 3)) << 4;
    const int aoff = ((wmi << 7) + lm) * 64 + f16off;
    const int boff = 16384 + ((wni << 6) + lm) * 64 + f16off;
    const int KT = K >> 6;

    f16x8 R[4][2];   // in-flight A fp16 (32 VGPR), static indexing only

    auto issue = [&](int bufoff, int kt) {
        const _Float16* a = gA + (long)kt * 64;
#pragma unroll
        for (int u = 0; u < 4; ++u) {
            R[u][0] = *(const f16x8*)(a + u * rstep);
            R[u][1] = *(const f16x8*)(a + u * rstep + 8);
        }
        const signed char* b = gB + ((long)kt << 6);
        gload_lds16(b,         lB + bufoff);
        gload_lds16(b + rstep, lB + bufoff + 4096);
    };

    auto qwrite = [&](int bufoff) {
#pragma unroll
        for (int u = 0; u < 4; ++u) {
            int qd[4];
#pragma unroll
            for (int d = 0; d < 4; ++d) {
                int pk = 0;
#pragma unroll
                for (int e = 0; e < 4; ++e) {
                    float h = (float)R[u][d >> 1][(d & 1) * 4 + e];
                    float q = rintf(fmaf(h, rs, zpf));
                    q = fminf(fmaxf(q, -128.0f), 127.0f);
                    pk |= ((int)q & 255) << (8 * e);
                }
                qd[d] = pk;
            }
            v4i qv = { qd[0], qd[1], qd[2], qd[3] };
            *(v4i*)(lA + bufoff + u * 4096) = qv;
        }
    };

    auto compute = [&](int bufoff) {
        v4i av[8], bv[4];
#pragma unroll
        for (int j = 0; j < 4; ++j)
            bv[j] = *(const v4i*)&Ls[bufoff + boff + j * 1024];
#pragma unroll
        for (int i = 0; i < 8; ++i)
            av[i] = *(const v4i*)&Ls[bufoff + aoff + i * 1024];
        __builtin_amdgcn_s_setprio(1);
#pragma unroll
        for (int i = 0; i < 8; ++i)
#pragma unroll
            for (int j = 0; j < 4; ++j)
                acc[i][j] = __builtin_amdgcn_mfma_i32_16x16x64_i8(av[i], bv[j], acc[i][j], 0, 0, 0);
        __builtin_amdgcn_s_setprio(0);
    };

    // prologue: tile 0 -> buffer 0
    issue(0, 0);
    asm volatile("s_waitcnt vmcnt(0)" ::: "memory");
    qwrite(0);
    asm volatile("s_waitcnt lgkmcnt(0)\n\ts_barrier" ::: "memory");

    for (int t = 0; t < KT; ++t) {
        const int cur = (t & 1) * 24576;
        const int nxt = 24576 - cur;
        if (t + 1 < KT) issue(nxt, t + 1);
        compute(cur);
        if (t + 1 < KT) {
            asm volatile("s_waitcnt vmcnt(0)" ::: "memory");
            qwrite(nxt);
            asm volatile("s_waitcnt lgkmcnt(0)\n\ts_barrier" ::: "memory");
        }
    }
}

__global__ __launch_bounds__(256, 2) void k_gemm1(const signed char* __restrict__ Aq,
                                                  const signed char* __restrict__ Bq,
                                                  _Float16* __restrict__ H,
                                                  const float* __restrict__ scal,
                                                  const int* __restrict__ iscal,
                                                  const int* __restrict__ rsum,
                                                  const float* __restrict__ bias,
                                                  unsigned* slots) {
    __shared__ __align__(16) signed char Ls[3 * 24576];   // 72KB -> 2 blocks/CU
    __shared__ float red[8];
    const int nb = D_HID / 128;
    const int m0 = (blockIdx.x / nb) * 256, n0 = (blockIdx.x % nb) * 128;
    v4i acc[8][4];
    v4i zero = {0, 0, 0, 0};
#pragma unroll
    for (int i = 0; i < 8; i++)
#pragma unroll
        for (int j = 0; j < 4; j++) acc[i][j] = zero;
    int8_mainloop256(Aq, Bq, D_IN, m0, n0, Ls, acc);

    const int tid = threadIdx.x, l = tid & 63, w = tid >> 6;
    const int lm = l & 15, lq = l >> 4;
    const int wmi = w >> 1, wni = w & 1;
    float s1 = scal[4];
    int zx = iscal[0];
    float lmin = 3.4e38f, lmax = -3.4e38f;

    // all waves done reading mainloop LDS before we overwrite it
    __syncthreads();

    // phase 1: GELU + ds_write_b16 into XOR-swizzled 256x128 fp16 tile (64KB).
#pragma unroll
    for (int j = 0; j < 4; j++) {
        int n = n0 + (wni << 6) + j * 16 + lm;
        int rsn = rsum[n];
        float bn = bias[n];
        int colb = ((wni << 6) + j * 16 + lm) * 2;   // byte col in tile
#pragma unroll
        for (int i = 0; i < 8; i++) {
#pragma unroll
            for (int rg = 0; rg < 4; rg++) {
                int row = (wmi << 7) + i * 16 + lq * 4 + rg;
                int v = acc[i][j][rg] - zx * rsn;
                float fv = (float)v * s1 + bn;
                float g = fv * 0.5f * (1.0f + fast_erf(fv * 0.7071067811865476f));
                _Float16 gh = (_Float16)g;
                int off = (row * 256 + colb) ^ (((row >> 2) & 7) << 5);
                *(_Float16*)&Ls[off] = gh;
                float gf = (float)gh;
                lmin = fminf(lmin, gf);
                lmax = fmaxf(lmax, gf);
            }
        }
    }
    __syncthreads();

    // phase 2: coalesced store — 16 rows/iter x 16 iters = 256 rows.
#pragma unroll
    for (int it = 0; it < 16; it++) {
        int row = it * 16 + (tid >> 4);
        int c = tid & 15;
        int off = (row * 256 + c * 16) ^ (((row >> 2) & 7) << 5);
        v4i d = *(const v4i*)&Ls[off];
        *(v4i*)&H[(long)(m0 + row) * D_HID + n0 + c * 8] = d;
    }

    // block h-min/max -> global atomic slots
    for (int off = 32; off > 0; off >>= 1) {
        lmin = fminf(lmin, __shfl_down(lmin, off));
        lmax = fmaxf(lmax, __shfl_down(lmax, off));
    }
    if (l == 0) { red[w] = lmin; red[4 + w] = lmax; }
    __syncthreads();
    if (tid == 0) {
        atomicMin(&slots[4], enc_f(fminf(fminf(red[0], red[1]), fminf(red[2], red[3]))));
        atomicMax(&slots[5], enc_f(fmaxf(fmaxf(red[4], red[5]), fmaxf(red[6], red[7]))));
    }
}

__global__ __launch_bounds__(256, 2) void k_gemm2(const _Float16* __restrict__ Hm,
                                                  const signed char* __restrict__ Bq,
                                                  float* __restrict__ Out,
                                                  const float* __restrict__ scal,
                                                  const unsigned* __restrict__ slots,
                                                  const int* __restrict__ rsum,
                                                  const float* __restrict__ bias) {
    __shared__ __align__(16) signed char Ls[2 * 24576];   // 48KB (regs cap at 2 blocks/CU)
    const int nb = D_IN / 128;
    const int m0 = (blockIdx.x / nb) * 256, n0 = (blockIdx.x % nb) * 128;
    v4i acc[8][4];
    v4i zero = {0, 0, 0, 0};
#pragma unroll
    for (int i = 0; i < 8; i++)
#pragma unroll
        for (int j = 0; j < 4; j++) acc[i][j] = zero;

    // stage-2 scales decoded inline from slots (same math as old k_scales2)
    float amin = dec_f(slots[4]), amax = dec_f(slots[5]);
    float sh = fmaxf((amax - amin) / 255.0f, 1e-8f);
    float zpf = rintf(-amin / sh) - 128.0f;
    zpf = fminf(fmaxf(zpf, -128.0f), 127.0f);
    float rs = 1.0f / sh;             // one exact IEEE division per thread
    float s2 = sh * scal[3];
    int zx = (int)zpf;

    int8_mainloop_h(Hm, Bq, D_HID, m0, n0, rs, zpf, Ls, acc);

    const int tid = threadIdx.x, l = tid & 63, w = tid >> 6;
    const int lm = l & 15, lq = l >> 4;
    const int wmi = w >> 1, wni = w & 1;
#pragma unroll
    for (int j = 0; j < 4; j++) {
        int n = n0 + (wni << 6) + j * 16 + lm;
        int rsn = rsum[n];
        float bn = bias[n];
#pragma unroll
        for (int i = 0; i < 8; i++) {
            int mb = m0 + (wmi << 7) + i * 16 + lq * 4;
#pragma unroll
            for (int rg = 0; rg < 4; rg++) {
                int v = acc[i][j][rg] - zx * rsn;
                Out[(long)(mb + rg) * D_IN + n] = (float)v * s2 + bn;
            }
        }
    }
}

extern "C" void kernel_launch(void* const* d_in, const int* in_sizes, int n_in,
                              void* d_out, int out_size, void* d_ws, size_t ws_size,
                              hipStream_t stream) {
    const float* x  = (const float*)d_in[0];
    const float* W1 = (const float*)d_in[1];
    const float* b1 = (const float*)d_in[2];
    const float* W2 = (const float*)d_in[3];
    const float* b2 = (const float*)d_in[4];

    char* ws = (char*)d_ws;
    unsigned* slots    = (unsigned*)(ws + OFF_SLOTS);
    float* scal        = (float*)(ws + OFF_SCAL);
    int* iscal         = (int*)(ws + OFF_ISCAL);
    signed char* xq    = (signed char*)(ws + OFF_XQ);
    signed char* w1q   = (signed char*)(ws + OFF_W1Q);
    signed char* w2q   = (signed char*)(ws + OFF_W2Q);
    int* rs1           = (int*)(ws + OFF_RS1);
    int* rs2           = (int*)(ws + OFF_RS2);
    _Float16* h        = (_Float16*)(ws + OFF_H);

    // reduction partials: written by k_reduce_all, read by k_quant_all, dead after.
    float* pxmin = (float*)(ws + OFF_PART);         // 1024 f32
    float* pxmax = pxmin + 1024;                    // 1024 f32
    float* pw1   = pxmax + 1024;                    // 256 f32
    float* pw2   = pw1 + 256;                       // 256 f32  (10KB total)

    k_reduce_all<<<1536, 256, 0, stream>>>((const float4*)x, (const float4*)W1,
                                           (const float4*)W2, pxmin, pxmax, pw1, pw2);
    k_quant_all<<<7168, 256, 0, stream>>>((const float4*)x, (int*)xq,
                                          W1, w1q, rs1, W2, w2q, rs2,
                                          pxmin, pxmax, pw1, pw2, scal, iscal, slots);
    k_gemm1<<<(M_TOK / 256) * (D_HID / 128), 256, 0, stream>>>(xq, w1q, h, scal, iscal, rs1, b1, slots);
    k_gemm2<<<(M_TOK / 256) * (D_IN / 128), 256, 0, stream>>>(h, w2q, (float*)d_out, scal, slots, rs2, b2);
}

// Round 11
// 419.244 us; speedup vs baseline: 1.0216x; 1.0216x over previous
//
#include <hip/hip_runtime.h>
#include <hip/hip_bf16.h>
#include <math.h>

// Problem dims (fixed by reference setup_inputs)
#define D_IN   1024
#define D_HID  4096
#define M_TOK  16384   // 4 * 4096 tokens

typedef int v4i __attribute__((ext_vector_type(4)));
typedef _Float16 f16x8 __attribute__((ext_vector_type(8)));

typedef __attribute__((address_space(3))) unsigned int lds_u32;
typedef const __attribute__((address_space(1))) unsigned int glb_u32;

// async global->LDS, 16B per lane, wave-uniform LDS base + lane*16
__device__ inline void gload_lds16(const signed char* g, signed char* l) {
    __builtin_amdgcn_global_load_lds((glb_u32*)g, (lds_u32*)l, 16, 0, 0);
}

// Branchless erf, Abramowitz-Stegun 7.1.26, |eps| <= 1.5e-7 (<< fp16-h rounding).
__device__ inline float fast_erf(float x) {
    float ax = fabsf(x);
    float t = __builtin_amdgcn_rcpf(fmaf(0.3275911f, ax, 1.0f));
    float y = t * (0.254829592f +
              t * (-0.284496736f +
              t * (1.421413741f +
              t * (-1.453152027f +
              t * 1.061405429f))));
    float e = __expf(-ax * ax);          // native v_exp path
    float r = fmaf(-y, e, 1.0f);
    return copysignf(r, x);
}

// ---------------- workspace layout (bytes) ----------------
#define OFF_SLOTS  ((size_t)0)                                   // 8 x u32 atomic slots
#define OFF_SCAL   ((size_t)64)                                  // 16 x f32 scalars
#define OFF_ISCAL  ((size_t)128)                                 // 8 x i32
#define OFF_XQ     ((size_t)256)                                 // 16M  int8
#define OFF_W1Q    (OFF_XQ  + (size_t)M_TOK * D_IN)              // 4M   int8
#define OFF_W2Q    (OFF_W1Q + (size_t)D_HID * D_IN)              // 4M   int8
#define OFF_RS1    (OFF_W2Q + (size_t)D_IN * D_HID)              // 16K  i32
#define OFF_RS2    (OFF_RS1 + (size_t)D_HID * 4)                 // 4K   i32
#define OFF_H      (OFF_RS2 + (size_t)D_IN * 4 + 128)            // 128M fp16
#define OFF_PART   (OFF_H   + (size_t)M_TOK * D_HID * 2)         // 10K  f32 partials
// hq workspace eliminated (R10): gemm2 quantizes H in-register during staging.
// Partials (k_reduce_all -> k_quant_all) live after H; never overwritten.

// slots: [4] h min(enc) [5] h max(enc)
// scal:  [0] sx1 [1] zx1f [2] sw1 [3] sw2 [4] s1=sx1*sw1   (written by quant_all blk 0)
// iscal: [0] zx1

__device__ inline unsigned enc_f(float f) {
    unsigned u = __float_as_uint(f);
    return (u & 0x80000000u) ? ~u : (u | 0x80000000u);
}
__device__ inline float dec_f(unsigned u) {
    return __uint_as_float((u & 0x80000000u) ? (u ^ 0x80000000u) : ~u);
}

// ---- fused stage-1 reductions: x min/max + |W1|max + |W2|max, deterministic partials
__global__ void k_reduce_all(const float4* __restrict__ x,
                             const float4* __restrict__ w1,
                             const float4* __restrict__ w2,
                             float* __restrict__ pxmin, float* __restrict__ pxmax,
                             float* __restrict__ pw1, float* __restrict__ pw2) {
    __shared__ float red[8];
    const int b = blockIdx.x;
    const int wave = threadIdx.x >> 6, lane = threadIdx.x & 63;
    if (b < 1024) {
        float vmin = 3.4e38f, vmax = -3.4e38f;
        for (int i = b * 256 + threadIdx.x; i < M_TOK * D_IN / 4; i += 1024 * 256) {
            float4 v = x[i];
            vmin = fminf(vmin, fminf(fminf(v.x, v.y), fminf(v.z, v.w)));
            vmax = fmaxf(vmax, fmaxf(fmaxf(v.x, v.y), fmaxf(v.z, v.w)));
        }
        for (int off = 32; off > 0; off >>= 1) {
            vmin = fminf(vmin, __shfl_down(vmin, off));
            vmax = fmaxf(vmax, __shfl_down(vmax, off));
        }
        if (lane == 0) { red[wave] = vmin; red[4 + wave] = vmax; }
        __syncthreads();
        if (threadIdx.x == 0) {
            pxmin[b] = fminf(fminf(red[0], red[1]), fminf(red[2], red[3]));
            pxmax[b] = fmaxf(fmaxf(red[4], red[5]), fmaxf(red[6], red[7]));
        }
    } else {
        const float4* w = (b < 1280) ? w1 : w2;
        const int bb = (b < 1280) ? b - 1024 : b - 1280;
        float vmax = 0.0f;
        for (int i = bb * 256 + threadIdx.x; i < D_HID * D_IN / 4; i += 256 * 256) {
            float4 v = w[i];
            vmax = fmaxf(vmax, fmaxf(fmaxf(fabsf(v.x), fabsf(v.y)), fmaxf(fabsf(v.z), fabsf(v.w))));
        }
        for (int off = 32; off > 0; off >>= 1)
            vmax = fmaxf(vmax, __shfl_down(vmax, off));
        if (lane == 0) red[wave] = vmax;
        __syncthreads();
        if (threadIdx.x == 0) {
            float bm = fmaxf(fmaxf(red[0], red[1]), fmaxf(red[2], red[3]));
            if (b < 1280) pw1[bb] = bm; else pw2[bb] = bm;
        }
    }
}

// ---- fused stage-1 quantization (scales folded in):
// x (blocks 0..2047), W1 rows (2048..6143), W2 rows (6144..7167).
__global__ void k_quant_all(const float4* __restrict__ x, int* __restrict__ xq,
                            const float* __restrict__ W1, signed char* __restrict__ w1q,
                            int* __restrict__ rs1,
                            const float* __restrict__ W2, signed char* __restrict__ w2q,
                            int* __restrict__ rs2,
                            const float* __restrict__ pxmin, const float* __restrict__ pxmax,
                            const float* __restrict__ pw1, const float* __restrict__ pw2,
                            float* __restrict__ scal, int* __restrict__ iscal,
                            unsigned* __restrict__ slots) {
    __shared__ float sred[8];
    __shared__ int red[4];
    const int b = blockIdx.x;
    const int wave = threadIdx.x >> 6, lane = threadIdx.x & 63;

    if (b < 2048) {
        float vmin = 3.4e38f, vmax = -3.4e38f;
        for (int i = threadIdx.x; i < 1024; i += 256) {
            vmin = fminf(vmin, pxmin[i]);
            vmax = fmaxf(vmax, pxmax[i]);
        }
        for (int off = 32; off > 0; off >>= 1) {
            vmin = fminf(vmin, __shfl_down(vmin, off));
            vmax = fmaxf(vmax, __shfl_down(vmax, off));
        }
        if (lane == 0) { sred[wave] = vmin; sred[4 + wave] = vmax; }
        __syncthreads();
        vmin = fminf(fminf(sred[0], sred[1]), fminf(sred[2], sred[3]));
        vmax = fmaxf(fmaxf(sred[4], sred[5]), fmaxf(sred[6], sred[7]));
        float s = fmaxf((vmax - vmin) / 255.0f, 1e-8f);
        float zp = rintf(-vmin / s) - 128.0f;
        zp = fminf(fmaxf(zp, -128.0f), 127.0f);

        if (b == 0 && threadIdx.x == 0) {
            float w1m = 0.0f, w2m = 0.0f;
            for (int i = 0; i < 256; i++) {
                w1m = fmaxf(w1m, pw1[i]);
                w2m = fmaxf(w2m, pw2[i]);
            }
            float sw1 = fmaxf(w1m / 127.0f, 1e-8f);
            float sw2 = fmaxf(w2m / 127.0f, 1e-8f);
            scal[0] = s; scal[1] = zp; scal[2] = sw1; scal[3] = sw2; scal[4] = s * sw1;
            iscal[0] = (int)zp;
            slots[4] = 0xFFFFFFFFu;   // h min (enc)
            slots[5] = 0u;            // h max (enc)
        }

        for (int i = b * 256 + threadIdx.x; i < M_TOK * D_IN / 4; i += 2048 * 256) {
            float4 v = x[i];
            int a0 = (int)fminf(fmaxf(rintf(v.x / s) + zp, -128.0f), 127.0f);
            int a1 = (int)fminf(fmaxf(rintf(v.y / s) + zp, -128.0f), 127.0f);
            int a2 = (int)fminf(fmaxf(rintf(v.z / s) + zp, -128.0f), 127.0f);
            int a3 = (int)fminf(fmaxf(rintf(v.w / s) + zp, -128.0f), 127.0f);
            xq[i] = (a0 & 255) | ((a1 & 255) << 8) | ((a2 & 255) << 16) | ((a3 & 255) << 24);
        }
        return;
    }

    const int isW1 = (b < 2048 + 4096);
    const int row = isW1 ? (b - 2048) : (b - 6144);
    const int K = isW1 ? D_IN : D_HID;
    const float* pw = isW1 ? pw1 : pw2;
    const float* W = isW1 ? W1 : W2;
    signed char* Wq = isW1 ? w1q : w2q;
    int* rsum = isW1 ? rs1 : rs2;

    float wm = pw[threadIdx.x & 255];
    for (int off = 32; off > 0; off >>= 1)
        wm = fmaxf(wm, __shfl_down(wm, off));
    if (lane == 0) sred[wave] = wm;
    __syncthreads();
    wm = fmaxf(fmaxf(sred[0], sred[1]), fmaxf(sred[2], sred[3]));
    const float s = fmaxf(wm / 127.0f, 1e-8f);

    const float4* Wr = (const float4*)(W + (size_t)row * K);
    int* out = (int*)(Wq + (size_t)row * K);
    int mysum = 0;
    for (int i = threadIdx.x; i < K / 4; i += 256) {
        float4 v = Wr[i];
        int a0 = (int)fminf(fmaxf(rintf(v.x / s), -127.0f), 127.0f);
        int a1 = (int)fminf(fmaxf(rintf(v.y / s), -127.0f), 127.0f);
        int a2 = (int)fminf(fmaxf(rintf(v.z / s), -127.0f), 127.0f);
        int a3 = (int)fminf(fmaxf(rintf(v.w / s), -127.0f), 127.0f);
        mysum += a0 + a1 + a2 + a3;
        out[i] = (a0 & 255) | ((a1 & 255) << 8) | ((a2 & 255) << 16) | ((a3 & 255) << 24);
    }
    for (int off = 32; off > 0; off >>= 1)
        mysum += __shfl_down(mysum, off);
    if (lane == 0) red[wave] = mysum;
    __syncthreads();
    if (threadIdx.x == 0) rsum[row] = red[0] + red[1] + red[2] + red[3];
}

// ---------------- int8 MFMA GEMM mainloop, 256x128 tile (gemm1) ----------------
// (R10-verified: triple-buffer, counted vmcnt(6), 1 barrier/tile. Closed
// levers: 3 blocks/CU spills acc [R6]; intra-block phase split regresses at
// 4 waves [R5]; XCD chunk-swizzle thrashes B in L2 [R8].)
__device__ inline void int8_mainloop256(const signed char* __restrict__ A,
                                        const signed char* __restrict__ B,
                                        int K, int m0, int n0,
                                        signed char* Ls, v4i (&acc)[8][4]) {
    const int tid = threadIdx.x;
    const int l = tid & 63, w = tid >> 6;
    const int lm = l & 15, lq = l >> 4;
    const int wmi = w >> 1, wni = w & 1;

    const int gc16 = ((l & 3) ^ ((l >> 3) & 3)) << 4;   // swizzled global chunk
    const int srow = (w << 4) + (l >> 2);               // rows 0..63 (+q*64)
    const signed char* gA = A + (long)(m0 + srow) * K + gc16;
    const signed char* gB = B + (long)(n0 + srow) * K + gc16;
    const long rstep = (long)K << 6;                    // 64 rows
    signed char* lA = Ls + (w << 10) + (l << 4);
    signed char* lB = Ls + 16384 + (w << 10) + (l << 4);

    const int f16off = (lq ^ ((lm >> 1) & 3)) << 4;
    const int aoff = ((wmi << 7) + lm) * 64 + f16off;
    const int boff = 16384 + ((wni << 6) + lm) * 64 + f16off;

    const int KT = K >> 6;

    auto stage = [&](int bufoff, int kt) {
        const signed char* a = gA + ((long)kt << 6);
        const signed char* b = gB + ((long)kt << 6);
        gload_lds16(a,             lA + bufoff);
        gload_lds16(a + rstep,     lA + bufoff + 4096);
        gload_lds16(a + 2 * rstep, lA + bufoff + 8192);
        gload_lds16(a + 3 * rstep, lA + bufoff + 12288);
        gload_lds16(b,             lB + bufoff);
        gload_lds16(b + rstep,     lB + bufoff + 4096);
    };

    auto compute = [&](int bufoff) {
        v4i av[8], bv[4];
#pragma unroll
        for (int j = 0; j < 4; ++j)
            bv[j] = *(const v4i*)&Ls[bufoff + boff + j * 1024];
#pragma unroll
        for (int i = 0; i < 8; ++i)
            av[i] = *(const v4i*)&Ls[bufoff + aoff + i * 1024];
        __builtin_amdgcn_s_setprio(1);
#pragma unroll
        for (int i = 0; i < 8; ++i)
#pragma unroll
            for (int j = 0; j < 4; ++j)
                acc[i][j] = __builtin_amdgcn_mfma_i32_16x16x64_i8(av[i], bv[j], acc[i][j], 0, 0, 0);
        __builtin_amdgcn_s_setprio(0);
    };

    stage(0, 0);
    stage(24576, 1);

    int b0 = 0, b1 = 24576, b2 = 49152;
    for (int t = 0; t < KT - 2; ++t) {
        asm volatile("s_waitcnt vmcnt(6)\n\ts_barrier" ::: "memory");
        stage(b2, t + 2);
        compute(b0);
        int tmp = b0; b0 = b1; b1 = b2; b2 = tmp;
    }
    asm volatile("s_waitcnt vmcnt(6)\n\ts_barrier" ::: "memory");
    compute(b0);
    asm volatile("s_waitcnt vmcnt(0)\n\ts_barrier" ::: "memory");
    compute(b1);
}

// ---------------- gemm2 mainloop: fp16 A with fused quantization ----------------
// (R10 structure, unchanged — see its step list and safety ledger.)
__device__ inline void int8_mainloop_h(const _Float16* __restrict__ Hm,
                                       const signed char* __restrict__ B,
                                       int K, int m0, int n0,
                                       float rs, float zpf,
                                       signed char* Ls, v4i (&acc)[8][4]) {
    const int tid = threadIdx.x;
    const int l = tid & 63, w = tid >> 6;
    const int lm = l & 15, lq = l >> 4;
    const int wmi = w >> 1, wni = w & 1;

    const int col0 = (l & 3) ^ ((l >> 3) & 3);          // swizzled 16-elem chunk
    const int srow = (w << 4) + (l >> 2);
    const _Float16* gA = Hm + (long)(m0 + srow) * K + col0 * 16;   // elements
    const signed char* gB = B + (long)(n0 + srow) * K + (col0 << 4);
    const long rstep = (long)K << 6;                    // 64 rows (elems==bytes)
    signed char* lA = Ls + (w << 10) + (l << 4);
    signed char* lB = Ls + 16384 + (w << 10) + (l << 4);

    const int f16off = (lq ^ ((lm >> 1) & 3)) << 4;
    const int aoff = ((wmi << 7) + lm) * 64 + f16off;
    const int boff = 16384 + ((wni << 6) + lm) * 64 + f16off;
    const int KT = K >> 6;

    f16x8 R[4][2];   // in-flight A fp16 (32 VGPR), static indexing only

    auto issue = [&](int bufoff, int kt) {
        const _Float16* a = gA + (long)kt * 64;
#pragma unroll
        for (int u = 0; u < 4; ++u) {
            R[u][0] = *(const f16x8*)(a + u * rstep);
            R[u][1] = *(const f16x8*)(a + u * rstep + 8);
        }
        const signed char* b = gB + ((long)kt << 6);
        gload_lds16(b,         lB + bufoff);
        gload_lds16(b + rstep, lB + bufoff + 4096);
    };

    auto qwrite = [&](int bufoff) {
#pragma unroll
        for (int u = 0; u < 4; ++u) {
            int qd[4];
#pragma unroll
            for (int d = 0; d < 4; ++d) {
                int pk = 0;
#pragma unroll
                for (int e = 0; e < 4; ++e) {
                    float h = (float)R[u][d >> 1][(d & 1) * 4 + e];
                    float q = rintf(fmaf(h, rs, zpf));
                    q = fminf(fmaxf(q, -128.0f), 127.0f);
                    pk |= ((int)q & 255) << (8 * e);
                }
                qd[d] = pk;
            }
            v4i qv = { qd[0], qd[1], qd[2], qd[3] };
            *(v4i*)(lA + bufoff + u * 4096) = qv;
        }
    };

    auto compute = [&](int bufoff) {
        v4i av[8], bv[4];
#pragma unroll
        for (int j = 0; j < 4; ++j)
            bv[j] = *(const v4i*)&Ls[bufoff + boff + j * 1024];
#pragma unroll
        for (int i = 0; i < 8; ++i)
            av[i] = *(const v4i*)&Ls[bufoff + aoff + i * 1024];
        __builtin_amdgcn_s_setprio(1);
#pragma unroll
        for (int i = 0; i < 8; ++i)
#pragma unroll
            for (int j = 0; j < 4; ++j)
                acc[i][j] = __builtin_amdgcn_mfma_i32_16x16x64_i8(av[i], bv[j], acc[i][j], 0, 0, 0);
        __builtin_amdgcn_s_setprio(0);
    };

    // prologue: tile 0 -> buffer 0
    issue(0, 0);
    asm volatile("s_waitcnt vmcnt(0)" ::: "memory");
    qwrite(0);
    asm volatile("s_waitcnt lgkmcnt(0)\n\ts_barrier" ::: "memory");

    for (int t = 0; t < KT; ++t) {
        const int cur = (t & 1) * 24576;
        const int nxt = 24576 - cur;
        if (t + 1 < KT) issue(nxt, t + 1);
        compute(cur);
        if (t + 1 < KT) {
            asm volatile("s_waitcnt vmcnt(0)" ::: "memory");
            qwrite(nxt);
            asm volatile("s_waitcnt lgkmcnt(0)\n\ts_barrier" ::: "memory");
        }
    }
}

__global__ __launch_bounds__(256, 2) void k_gemm1(const signed char* __restrict__ Aq,
                                                  const signed char* __restrict__ Bq,
                                                  _Float16* __restrict__ H,
                                                  const float* __restrict__ scal,
                                                  const int* __restrict__ iscal,
                                                  const int* __restrict__ rsum,
                                                  const float* __restrict__ bias,
                                                  unsigned* slots) {
    __shared__ __align__(16) signed char Ls[3 * 24576];   // 72KB -> 2 blocks/CU
    __shared__ float red[8];
    const int nb = D_HID / 128;
    const int m0 = (blockIdx.x / nb) * 256, n0 = (blockIdx.x % nb) * 128;
    v4i acc[8][4];
    v4i zero = {0, 0, 0, 0};
#pragma unroll
    for (int i = 0; i < 8; i++)
#pragma unroll
        for (int j = 0; j < 4; j++) acc[i][j] = zero;
    int8_mainloop256(Aq, Bq, D_IN, m0, n0, Ls, acc);

    const int tid = threadIdx.x, l = tid & 63, w = tid >> 6;
    const int lm = l & 15, lq = l >> 4;
    const int wmi = w >> 1, wni = w & 1;
    float s1 = scal[4];
    int zx = iscal[0];
    float lmin = 3.4e38f, lmax = -3.4e38f;

    // all waves done reading mainloop LDS before we overwrite it
    __syncthreads();

    // phase 1: GELU + ds_write_b16 into XOR-swizzled 256x128 fp16 tile (64KB).
#pragma unroll
    for (int j = 0; j < 4; j++) {
        int n = n0 + (wni << 6) + j * 16 + lm;
        int rsn = rsum[n];
        float bn = bias[n];
        int colb = ((wni << 6) + j * 16 + lm) * 2;   // byte col in tile
#pragma unroll
        for (int i = 0; i < 8; i++) {
#pragma unroll
            for (int rg = 0; rg < 4; rg++) {
                int row = (wmi << 7) + i * 16 + lq * 4 + rg;
                int v = acc[i][j][rg] - zx * rsn;
                float fv = (float)v * s1 + bn;
                float g = fv * 0.5f * (1.0f + fast_erf(fv * 0.7071067811865476f));
                _Float16 gh = (_Float16)g;
                int off = (row * 256 + colb) ^ (((row >> 2) & 7) << 5);
                *(_Float16*)&Ls[off] = gh;
                float gf = (float)gh;
                lmin = fminf(lmin, gf);
                lmax = fmaxf(lmax, gf);
            }
        }
    }
    __syncthreads();

    // phase 2: coalesced store — 16 rows/iter x 16 iters = 256 rows.
#pragma unroll
    for (int it = 0; it < 16; it++) {
        int row = it * 16 + (tid >> 4);
        int c = tid & 15;
        int off = (row * 256 + c * 16) ^ (((row >> 2) & 7) << 5);
        v4i d = *(const v4i*)&Ls[off];
        *(v4i*)&H[(long)(m0 + row) * D_HID + n0 + c * 8] = d;
    }

    // block h-min/max -> global atomic slots
    for (int off = 32; off > 0; off >>= 1) {
        lmin = fminf(lmin, __shfl_down(lmin, off));
        lmax = fmaxf(lmax, __shfl_down(lmax, off));
    }
    if (l == 0) { red[w] = lmin; red[4 + w] = lmax; }
    __syncthreads();
    if (tid == 0) {
        atomicMin(&slots[4], enc_f(fminf(fminf(red[0], red[1]), fminf(red[2], red[3]))));
        atomicMax(&slots[5], enc_f(fmaxf(fmaxf(red[4], red[5]), fmaxf(red[6], red[7]))));
    }
}

__global__ __launch_bounds__(256, 2) void k_gemm2(const _Float16* __restrict__ Hm,
                                                  const signed char* __restrict__ Bq,
                                                  float* __restrict__ Out,
                                                  const float* __restrict__ scal,
                                                  const unsigned* __restrict__ slots,
                                                  const int* __restrict__ rsum,
                                                  const float* __restrict__ bias) {
    __shared__ __align__(16) signed char Ls[2 * 24576];   // 48KB (regs cap at 2 blocks/CU)
    // R11: m-INNER block mapping. The 8 blocks sharing A-stripe m have IDs
    // {64n+m} == m (mod 8) -> SAME XCD under round-robin assignment (R8/R10
    // evidence) -> A K-chunks fetched once into that XCD's L2, read 8x from
    // L2 instead of 8x from HBM (R10 m-major: FETCH 528MB, 45% HBM-bound).
    // B becomes the cross-XCD operand but is only 4MB total (8x = 32MB).
    const int m0 = (blockIdx.x & 63) * 256;   // m inner: 64 m-groups
    const int n0 = (blockIdx.x >> 6) * 128;   // n outer: 8 n-panels
    v4i acc[8][4];
    v4i zero = {0, 0, 0, 0};
#pragma unroll
    for (int i = 0; i < 8; i++)
#pragma unroll
        for (int j = 0; j < 4; j++) acc[i][j] = zero;

    // stage-2 scales decoded inline from slots (same math as old k_scales2)
    float amin = dec_f(slots[4]), amax = dec_f(slots[5]);
    float sh = fmaxf((amax - amin) / 255.0f, 1e-8f);
    float zpf = rintf(-amin / sh) - 128.0f;
    zpf = fminf(fmaxf(zpf, -128.0f), 127.0f);
    float rs = 1.0f / sh;             // one exact IEEE division per thread
    float s2 = sh * scal[3];
    int zx = (int)zpf;

    int8_mainloop_h(Hm, Bq, D_HID, m0, n0, rs, zpf, Ls, acc);

    const int tid = threadIdx.x, l = tid & 63, w = tid >> 6;
    const int lm = l & 15, lq = l >> 4;
    const int wmi = w >> 1, wni = w & 1;
#pragma unroll
    for (int j = 0; j < 4; j++) {
        int n = n0 + (wni << 6) + j * 16 + lm;
        int rsn = rsum[n];
        float bn = bias[n];
#pragma unroll
        for (int i = 0; i < 8; i++) {
            int mb = m0 + (wmi << 7) + i * 16 + lq * 4;
#pragma unroll
            for (int rg = 0; rg < 4; rg++) {
                int v = acc[i][j][rg] - zx * rsn;
                Out[(long)(mb + rg) * D_IN + n] = (float)v * s2 + bn;
            }
        }
    }
}

extern "C" void kernel_launch(void* const* d_in, const int* in_sizes, int n_in,
                              void* d_out, int out_size, void* d_ws, size_t ws_size,
                              hipStream_t stream) {
    const float* x  = (const float*)d_in[0];
    const float* W1 = (const float*)d_in[1];
    const float* b1 = (const float*)d_in[2];
    const float* W2 = (const float*)d_in[3];
    const float* b2 = (const float*)d_in[4];

    char* ws = (char*)d_ws;
    unsigned* slots    = (unsigned*)(ws + OFF_SLOTS);
    float* scal        = (float*)(ws + OFF_SCAL);
    int* iscal         = (int*)(ws + OFF_ISCAL);
    signed char* xq    = (signed char*)(ws + OFF_XQ);
    signed char* w1q   = (signed char*)(ws + OFF_W1Q);
    signed char* w2q   = (signed char*)(ws + OFF_W2Q);
    int* rs1           = (int*)(ws + OFF_RS1);
    int* rs2           = (int*)(ws + OFF_RS2);
    _Float16* h        = (_Float16*)(ws + OFF_H);

    // reduction partials: written by k_reduce_all, read by k_quant_all, dead after.
    float* pxmin = (float*)(ws + OFF_PART);         // 1024 f32
    float* pxmax = pxmin + 1024;                    // 1024 f32
    float* pw1   = pxmax + 1024;                    // 256 f32
    float* pw2   = pw1 + 256;                       // 256 f32  (10KB total)

    k_reduce_all<<<1536, 256, 0, stream>>>((const float4*)x, (const float4*)W1,
                                           (const float4*)W2, pxmin, pxmax, pw1, pw2);
    k_quant_all<<<7168, 256, 0, stream>>>((const float4*)x, (int*)xq,
                                          W1, w1q, rs1, W2, w2q, rs2,
                                          pxmin, pxmax, pw1, pw2, scal, iscal, slots);
    k_gemm1<<<(M_TOK / 256) * (D_HID / 128), 256, 0, stream>>>(xq, w1q, h, scal, iscal, rs1, b1, slots);
    k_gemm2<<<(M_TOK / 256) * (D_IN / 128), 256, 0, stream>>>(h, w2q, (float*)d_out, scal, slots, rs2, b2);
}

// Round 12
// 369.284 us; speedup vs baseline: 1.1598x; 1.1353x over previous
//
#include <hip/hip_runtime.h>
#include <hip/hip_bf16.h>
#include <math.h>

// Problem dims (fixed by reference setup_inputs)
#define D_IN   1024
#define D_HID  4096
#define M_TOK  16384   // 4 * 4096 tokens

typedef int v4i __attribute__((ext_vector_type(4)));
typedef _Float16 f16x8 __attribute__((ext_vector_type(8)));

typedef __attribute__((address_space(3))) unsigned int lds_u32;
typedef const __attribute__((address_space(1))) unsigned int glb_u32;

// async global->LDS, 16B per lane, wave-uniform LDS base + lane*16
__device__ inline void gload_lds16(const signed char* g, signed char* l) {
    __builtin_amdgcn_global_load_lds((glb_u32*)g, (lds_u32*)l, 16, 0, 0);
}

// Branchless erf, Abramowitz-Stegun 7.1.26, |eps| <= 1.5e-7 (<< fp16-h rounding).
__device__ inline float fast_erf(float x) {
    float ax = fabsf(x);
    float t = __builtin_amdgcn_rcpf(fmaf(0.3275911f, ax, 1.0f));
    float y = t * (0.254829592f +
              t * (-0.284496736f +
              t * (1.421413741f +
              t * (-1.453152027f +
              t * 1.061405429f))));
    float e = __expf(-ax * ax);          // native v_exp path
    float r = fmaf(-y, e, 1.0f);
    return copysignf(r, x);
}

// ---------------- workspace layout (bytes) ----------------
#define OFF_SLOTS  ((size_t)0)                                   // 8 x u32 atomic slots
#define OFF_SCAL   ((size_t)64)                                  // 16 x f32 scalars
#define OFF_ISCAL  ((size_t)128)                                 // 8 x i32
#define OFF_XQ     ((size_t)256)                                 // 16M  int8
#define OFF_W1Q    (OFF_XQ  + (size_t)M_TOK * D_IN)              // 4M   int8
#define OFF_W2Q    (OFF_W1Q + (size_t)D_HID * D_IN)              // 4M   int8
#define OFF_RS1    (OFF_W2Q + (size_t)D_IN * D_HID)              // 16K  i32
#define OFF_RS2    (OFF_RS1 + (size_t)D_HID * 4)                 // 4K   i32
#define OFF_H      (OFF_RS2 + (size_t)D_IN * 4 + 128)            // 128M fp16
#define OFF_PART   (OFF_H   + (size_t)M_TOK * D_HID * 2)         // 10K  f32 partials
// hq workspace eliminated (R10): gemm2 quantizes H in-register during staging.
// Partials (k_reduce_all -> k_quant_all) live after H; never overwritten.

// slots: [4] h min(enc) [5] h max(enc)
// scal:  [0] sx1 [1] zx1f [2] sw1 [3] sw2 [4] s1=sx1*sw1   (written by quant_all blk 0)
// iscal: [0] zx1

// fp32 magic: 1.5*2^23. For t in [2^23,2^24) ulp=1, so fmaf(h,rs,zpf+MAGIC)
// single-RNE-rounds h*rs+zpf to an integer (== rint, bit-exact or better than
// rint(fmaf(..)) double rounding), and since MAGIC % 256 == 0 the int8 byte
// is float_as_uint(t)&255 directly — no v_rndne / v_cvt_i32 needed.
#define MAGIC 12582912.0f

__device__ inline unsigned enc_f(float f) {
    unsigned u = __float_as_uint(f);
    return (u & 0x80000000u) ? ~u : (u | 0x80000000u);
}
__device__ inline float dec_f(unsigned u) {
    return __uint_as_float((u & 0x80000000u) ? (u ^ 0x80000000u) : ~u);
}

// ---- fused stage-1 reductions: x min/max + |W1|max + |W2|max, deterministic partials
__global__ void k_reduce_all(const float4* __restrict__ x,
                             const float4* __restrict__ w1,
                             const float4* __restrict__ w2,
                             float* __restrict__ pxmin, float* __restrict__ pxmax,
                             float* __restrict__ pw1, float* __restrict__ pw2) {
    __shared__ float red[8];
    const int b = blockIdx.x;
    const int wave = threadIdx.x >> 6, lane = threadIdx.x & 63;
    if (b < 1024) {
        float vmin = 3.4e38f, vmax = -3.4e38f;
        for (int i = b * 256 + threadIdx.x; i < M_TOK * D_IN / 4; i += 1024 * 256) {
            float4 v = x[i];
            vmin = fminf(vmin, fminf(fminf(v.x, v.y), fminf(v.z, v.w)));
            vmax = fmaxf(vmax, fmaxf(fmaxf(v.x, v.y), fmaxf(v.z, v.w)));
        }
        for (int off = 32; off > 0; off >>= 1) {
            vmin = fminf(vmin, __shfl_down(vmin, off));
            vmax = fmaxf(vmax, __shfl_down(vmax, off));
        }
        if (lane == 0) { red[wave] = vmin; red[4 + wave] = vmax; }
        __syncthreads();
        if (threadIdx.x == 0) {
            pxmin[b] = fminf(fminf(red[0], red[1]), fminf(red[2], red[3]));
            pxmax[b] = fmaxf(fmaxf(red[4], red[5]), fmaxf(red[6], red[7]));
        }
    } else {
        const float4* w = (b < 1280) ? w1 : w2;
        const int bb = (b < 1280) ? b - 1024 : b - 1280;
        float vmax = 0.0f;
        for (int i = bb * 256 + threadIdx.x; i < D_HID * D_IN / 4; i += 256 * 256) {
            float4 v = w[i];
            vmax = fmaxf(vmax, fmaxf(fmaxf(fabsf(v.x), fabsf(v.y)), fmaxf(fabsf(v.z), fabsf(v.w))));
        }
        for (int off = 32; off > 0; off >>= 1)
            vmax = fmaxf(vmax, __shfl_down(vmax, off));
        if (lane == 0) red[wave] = vmax;
        __syncthreads();
        if (threadIdx.x == 0) {
            float bm = fmaxf(fmaxf(red[0], red[1]), fmaxf(red[2], red[3]));
            if (b < 1280) pw1[bb] = bm; else pw2[bb] = bm;
        }
    }
}

// ---- fused stage-1 quantization (scales folded in):
// x (blocks 0..2047), W1 rows (2048..6143), W2 rows (6144..7167).
__global__ void k_quant_all(const float4* __restrict__ x, int* __restrict__ xq,
                            const float* __restrict__ W1, signed char* __restrict__ w1q,
                            int* __restrict__ rs1,
                            const float* __restrict__ W2, signed char* __restrict__ w2q,
                            int* __restrict__ rs2,
                            const float* __restrict__ pxmin, const float* __restrict__ pxmax,
                            const float* __restrict__ pw1, const float* __restrict__ pw2,
                            float* __restrict__ scal, int* __restrict__ iscal,
                            unsigned* __restrict__ slots) {
    __shared__ float sred[8];
    __shared__ int red[4];
    const int b = blockIdx.x;
    const int wave = threadIdx.x >> 6, lane = threadIdx.x & 63;

    if (b < 2048) {
        float vmin = 3.4e38f, vmax = -3.4e38f;
        for (int i = threadIdx.x; i < 1024; i += 256) {
            vmin = fminf(vmin, pxmin[i]);
            vmax = fmaxf(vmax, pxmax[i]);
        }
        for (int off = 32; off > 0; off >>= 1) {
            vmin = fminf(vmin, __shfl_down(vmin, off));
            vmax = fmaxf(vmax, __shfl_down(vmax, off));
        }
        if (lane == 0) { sred[wave] = vmin; sred[4 + wave] = vmax; }
        __syncthreads();
        vmin = fminf(fminf(sred[0], sred[1]), fminf(sred[2], sred[3]));
        vmax = fmaxf(fmaxf(sred[4], sred[5]), fmaxf(sred[6], sred[7]));
        float s = fmaxf((vmax - vmin) / 255.0f, 1e-8f);
        float zp = rintf(-vmin / s) - 128.0f;
        zp = fminf(fmaxf(zp, -128.0f), 127.0f);

        if (b == 0 && threadIdx.x == 0) {
            float w1m = 0.0f, w2m = 0.0f;
            for (int i = 0; i < 256; i++) {
                w1m = fmaxf(w1m, pw1[i]);
                w2m = fmaxf(w2m, pw2[i]);
            }
            float sw1 = fmaxf(w1m / 127.0f, 1e-8f);
            float sw2 = fmaxf(w2m / 127.0f, 1e-8f);
            scal[0] = s; scal[1] = zp; scal[2] = sw1; scal[3] = sw2; scal[4] = s * sw1;
            iscal[0] = (int)zp;
            slots[4] = 0xFFFFFFFFu;   // h min (enc)
            slots[5] = 0u;            // h max (enc)
        }

        for (int i = b * 256 + threadIdx.x; i < M_TOK * D_IN / 4; i += 2048 * 256) {
            float4 v = x[i];
            int a0 = (int)fminf(fmaxf(rintf(v.x / s) + zp, -128.0f), 127.0f);
            int a1 = (int)fminf(fmaxf(rintf(v.y / s) + zp, -128.0f), 127.0f);
            int a2 = (int)fminf(fmaxf(rintf(v.z / s) + zp, -128.0f), 127.0f);
            int a3 = (int)fminf(fmaxf(rintf(v.w / s) + zp, -128.0f), 127.0f);
            xq[i] = (a0 & 255) | ((a1 & 255) << 8) | ((a2 & 255) << 16) | ((a3 & 255) << 24);
        }
        return;
    }

    const int isW1 = (b < 2048 + 4096);
    const int row = isW1 ? (b - 2048) : (b - 6144);
    const int K = isW1 ? D_IN : D_HID;
    const float* pw = isW1 ? pw1 : pw2;
    const float* W = isW1 ? W1 : W2;
    signed char* Wq = isW1 ? w1q : w2q;
    int* rsum = isW1 ? rs1 : rs2;

    float wm = pw[threadIdx.x & 255];
    for (int off = 32; off > 0; off >>= 1)
        wm = fmaxf(wm, __shfl_down(wm, off));
    if (lane == 0) sred[wave] = wm;
    __syncthreads();
    wm = fmaxf(fmaxf(sred[0], sred[1]), fmaxf(sred[2], sred[3]));
    const float s = fmaxf(wm / 127.0f, 1e-8f);

    const float4* Wr = (const float4*)(W + (size_t)row * K);
    int* out = (int*)(Wq + (size_t)row * K);
    int mysum = 0;
    for (int i = threadIdx.x; i < K / 4; i += 256) {
        float4 v = Wr[i];
        int a0 = (int)fminf(fmaxf(rintf(v.x / s), -127.0f), 127.0f);
        int a1 = (int)fminf(fmaxf(rintf(v.y / s), -127.0f), 127.0f);
        int a2 = (int)fminf(fmaxf(rintf(v.z / s), -127.0f), 127.0f);
        int a3 = (int)fminf(fmaxf(rintf(v.w / s), -127.0f), 127.0f);
        mysum += a0 + a1 + a2 + a3;
        out[i] = (a0 & 255) | ((a1 & 255) << 8) | ((a2 & 255) << 16) | ((a3 & 255) << 24);
    }
    for (int off = 32; off > 0; off >>= 1)
        mysum += __shfl_down(mysum, off);
    if (lane == 0) red[wave] = mysum;
    __syncthreads();
    if (threadIdx.x == 0) rsum[row] = red[0] + red[1] + red[2] + red[3];
}

// ---------------- int8 MFMA GEMM mainloop, 256x128 tile (gemm1) ----------------
// (R10-verified: triple-buffer, counted vmcnt(6), 1 barrier/tile. Closed
// levers: 3 blocks/CU spills acc [R6]; intra-block phase split regresses at
// 4 waves [R5]; XCD chunk-swizzle thrashes B in L2 [R8].)
__device__ inline void int8_mainloop256(const signed char* __restrict__ A,
                                        const signed char* __restrict__ B,
                                        int K, int m0, int n0,
                                        signed char* Ls, v4i (&acc)[8][4]) {
    const int tid = threadIdx.x;
    const int l = tid & 63, w = tid >> 6;
    const int lm = l & 15, lq = l >> 4;
    const int wmi = w >> 1, wni = w & 1;

    const int gc16 = ((l & 3) ^ ((l >> 3) & 3)) << 4;   // swizzled global chunk
    const int srow = (w << 4) + (l >> 2);               // rows 0..63 (+q*64)
    const signed char* gA = A + (long)(m0 + srow) * K + gc16;
    const signed char* gB = B + (long)(n0 + srow) * K + gc16;
    const long rstep = (long)K << 6;                    // 64 rows
    signed char* lA = Ls + (w << 10) + (l << 4);
    signed char* lB = Ls + 16384 + (w << 10) + (l << 4);

    const int f16off = (lq ^ ((lm >> 1) & 3)) << 4;
    const int aoff = ((wmi << 7) + lm) * 64 + f16off;
    const int boff = 16384 + ((wni << 6) + lm) * 64 + f16off;

    const int KT = K >> 6;

    auto stage = [&](int bufoff, int kt) {
        const signed char* a = gA + ((long)kt << 6);
        const signed char* b = gB + ((long)kt << 6);
        gload_lds16(a,             lA + bufoff);
        gload_lds16(a + rstep,     lA + bufoff + 4096);
        gload_lds16(a + 2 * rstep, lA + bufoff + 8192);
        gload_lds16(a + 3 * rstep, lA + bufoff + 12288);
        gload_lds16(b,             lB + bufoff);
        gload_lds16(b + rstep,     lB + bufoff + 4096);
    };

    auto compute = [&](int bufoff) {
        v4i av[8], bv[4];
#pragma unroll
        for (int j = 0; j < 4; ++j)
            bv[j] = *(const v4i*)&Ls[bufoff + boff + j * 1024];
#pragma unroll
        for (int i = 0; i < 8; ++i)
            av[i] = *(const v4i*)&Ls[bufoff + aoff + i * 1024];
        __builtin_amdgcn_s_setprio(1);
#pragma unroll
        for (int i = 0; i < 8; ++i)
#pragma unroll
            for (int j = 0; j < 4; ++j)
                acc[i][j] = __builtin_amdgcn_mfma_i32_16x16x64_i8(av[i], bv[j], acc[i][j], 0, 0, 0);
        __builtin_amdgcn_s_setprio(0);
    };

    stage(0, 0);
    stage(24576, 1);

    int b0 = 0, b1 = 24576, b2 = 49152;
    for (int t = 0; t < KT - 2; ++t) {
        asm volatile("s_waitcnt vmcnt(6)\n\ts_barrier" ::: "memory");
        stage(b2, t + 2);
        compute(b0);
        int tmp = b0; b0 = b1; b1 = b2; b2 = tmp;
    }
    asm volatile("s_waitcnt vmcnt(6)\n\ts_barrier" ::: "memory");
    compute(b0);
    asm volatile("s_waitcnt vmcnt(0)\n\ts_barrier" ::: "memory");
    compute(b1);
}

// ---------------- gemm2 mainloop: fp16 A with fused quantization ----------------
// (R10 structure + R11 m-inner mapping. R12: magic-number quantization —
// fmaf(h, rs, zpm) with zpm = zpf + MAGIC single-RNE-rounds to integer at
// ulp=1, clamp in shifted domain, byte = float_bits & 255. Saves v_rndne +
// v_cvt_i32 per element; conversion runs 8x redundant (one per consuming
// n-block), so each saved op counts 8x.)
__device__ inline void int8_mainloop_h(const _Float16* __restrict__ Hm,
                                       const signed char* __restrict__ B,
                                       int K, int m0, int n0,
                                       float rs, float zpm,
                                       signed char* Ls, v4i (&acc)[8][4]) {
    const int tid = threadIdx.x;
    const int l = tid & 63, w = tid >> 6;
    const int lm = l & 15, lq = l >> 4;
    const int wmi = w >> 1, wni = w & 1;

    const int col0 = (l & 3) ^ ((l >> 3) & 3);          // swizzled 16-elem chunk
    const int srow = (w << 4) + (l >> 2);
    const _Float16* gA = Hm + (long)(m0 + srow) * K + col0 * 16;   // elements
    const signed char* gB = B + (long)(n0 + srow) * K + (col0 << 4);
    const long rstep = (long)K << 6;                    // 64 rows (elems==bytes)
    signed char* lA = Ls + (w << 10) + (l << 4);
    signed char* lB = Ls + 16384 + (w << 10) + (l << 4);

    const int f16off = (lq ^ ((lm >> 1) & 3)) << 4;
    const int aoff = ((wmi << 7) + lm) * 64 + f16off;
    const int boff = 16384 + ((wni << 6) + lm) * 64 + f16off;
    const int KT = K >> 6;

    f16x8 R[4][2];   // in-flight A fp16 (32 VGPR), static indexing only

    auto issue = [&](int bufoff, int kt) {
        const _Float16* a = gA + (long)kt * 64;
#pragma unroll
        for (int u = 0; u < 4; ++u) {
            R[u][0] = *(const f16x8*)(a + u * rstep);
            R[u][1] = *(const f16x8*)(a + u * rstep + 8);
        }
        const signed char* b = gB + ((long)kt << 6);
        gload_lds16(b,         lB + bufoff);
        gload_lds16(b + rstep, lB + bufoff + 4096);
    };

    auto qwrite = [&](int bufoff) {
#pragma unroll
        for (int u = 0; u < 4; ++u) {
            int qd[4];
#pragma unroll
            for (int d = 0; d < 4; ++d) {
                unsigned pk = 0;
#pragma unroll
                for (int e = 0; e < 4; ++e) {
                    float h = (float)R[u][d >> 1][(d & 1) * 4 + e];
                    float t = fmaf(h, rs, zpm);    // RNE at ulp=1 == rint + MAGIC
                    t = fminf(fmaxf(t, MAGIC - 128.0f), MAGIC + 127.0f);
                    pk |= (__float_as_uint(t) & 255u) << (8 * e);
                }
                qd[d] = (int)pk;
            }
            v4i qv = { qd[0], qd[1], qd[2], qd[3] };
            *(v4i*)(lA + bufoff + u * 4096) = qv;
        }
    };

    auto compute = [&](int bufoff) {
        v4i av[8], bv[4];
#pragma unroll
        for (int j = 0; j < 4; ++j)
            bv[j] = *(const v4i*)&Ls[bufoff + boff + j * 1024];
#pragma unroll
        for (int i = 0; i < 8; ++i)
            av[i] = *(const v4i*)&Ls[bufoff + aoff + i * 1024];
        __builtin_amdgcn_s_setprio(1);
#pragma unroll
        for (int i = 0; i < 8; ++i)
#pragma unroll
            for (int j = 0; j < 4; ++j)
                acc[i][j] = __builtin_amdgcn_mfma_i32_16x16x64_i8(av[i], bv[j], acc[i][j], 0, 0, 0);
        __builtin_amdgcn_s_setprio(0);
    };

    // prologue: tile 0 -> buffer 0
    issue(0, 0);
    asm volatile("s_waitcnt vmcnt(0)" ::: "memory");
    qwrite(0);
    asm volatile("s_waitcnt lgkmcnt(0)\n\ts_barrier" ::: "memory");

    for (int t = 0; t < KT; ++t) {
        const int cur = (t & 1) * 24576;
        const int nxt = 24576 - cur;
        if (t + 1 < KT) issue(nxt, t + 1);
        compute(cur);
        if (t + 1 < KT) {
            asm volatile("s_waitcnt vmcnt(0)" ::: "memory");
            qwrite(nxt);
            asm volatile("s_waitcnt lgkmcnt(0)\n\ts_barrier" ::: "memory");
        }
    }
}

__global__ __launch_bounds__(256, 2) void k_gemm1(const signed char* __restrict__ Aq,
                                                  const signed char* __restrict__ Bq,
                                                  _Float16* __restrict__ H,
                                                  const float* __restrict__ scal,
                                                  const int* __restrict__ iscal,
                                                  const int* __restrict__ rsum,
                                                  const float* __restrict__ bias,
                                                  unsigned* slots) {
    __shared__ __align__(16) signed char Ls[3 * 24576];   // 72KB -> 2 blocks/CU
    __shared__ float red[8];
    const int nb = D_HID / 128;
    const int m0 = (blockIdx.x / nb) * 256, n0 = (blockIdx.x % nb) * 128;
    v4i acc[8][4];
    v4i zero = {0, 0, 0, 0};
#pragma unroll
    for (int i = 0; i < 8; i++)
#pragma unroll
        for (int j = 0; j < 4; j++) acc[i][j] = zero;
    int8_mainloop256(Aq, Bq, D_IN, m0, n0, Ls, acc);

    const int tid = threadIdx.x, l = tid & 63, w = tid >> 6;
    const int lm = l & 15, lq = l >> 4;
    const int wmi = w >> 1, wni = w & 1;
    float s1 = scal[4];
    int zx = iscal[0];
    float lmin = 3.4e38f, lmax = -3.4e38f;

    // all waves done reading mainloop LDS before we overwrite it
    __syncthreads();

    // phase 1: GELU + ds_write_b16 into XOR-swizzled 256x128 fp16 tile (64KB).
#pragma unroll
    for (int j = 0; j < 4; j++) {
        int n = n0 + (wni << 6) + j * 16 + lm;
        int rsn = rsum[n];
        float bn = bias[n];
        int colb = ((wni << 6) + j * 16 + lm) * 2;   // byte col in tile
#pragma unroll
        for (int i = 0; i < 8; i++) {
#pragma unroll
            for (int rg = 0; rg < 4; rg++) {
                int row = (wmi << 7) + i * 16 + lq * 4 + rg;
                int v = acc[i][j][rg] - zx * rsn;
                float fv = (float)v * s1 + bn;
                float g = fv * 0.5f * (1.0f + fast_erf(fv * 0.7071067811865476f));
                _Float16 gh = (_Float16)g;
                int off = (row * 256 + colb) ^ (((row >> 2) & 7) << 5);
                *(_Float16*)&Ls[off] = gh;
                float gf = (float)gh;
                lmin = fminf(lmin, gf);
                lmax = fmaxf(lmax, gf);
            }
        }
    }
    __syncthreads();

    // phase 2: coalesced store — 16 rows/iter x 16 iters = 256 rows.
#pragma unroll
    for (int it = 0; it < 16; it++) {
        int row = it * 16 + (tid >> 4);
        int c = tid & 15;
        int off = (row * 256 + c * 16) ^ (((row >> 2) & 7) << 5);
        v4i d = *(const v4i*)&Ls[off];
        *(v4i*)&H[(long)(m0 + row) * D_HID + n0 + c * 8] = d;
    }

    // block h-min/max -> global atomic slots
    for (int off = 32; off > 0; off >>= 1) {
        lmin = fminf(lmin, __shfl_down(lmin, off));
        lmax = fmaxf(lmax, __shfl_down(lmax, off));
    }
    if (l == 0) { red[w] = lmin; red[4 + w] = lmax; }
    __syncthreads();
    if (tid == 0) {
        atomicMin(&slots[4], enc_f(fminf(fminf(red[0], red[1]), fminf(red[2], red[3]))));
        atomicMax(&slots[5], enc_f(fmaxf(fmaxf(red[4], red[5]), fmaxf(red[6], red[7]))));
    }
}

__global__ __launch_bounds__(256, 2) void k_gemm2(const _Float16* __restrict__ Hm,
                                                  const signed char* __restrict__ Bq,
                                                  float* __restrict__ Out,
                                                  const float* __restrict__ scal,
                                                  const unsigned* __restrict__ slots,
                                                  const int* __restrict__ rsum,
                                                  const float* __restrict__ bias) {
    __shared__ __align__(16) signed char Ls[2 * 24576];   // 48KB (regs cap at 2 blocks/CU)
    // R11-verified m-INNER mapping: the 8 blocks sharing A-stripe m have IDs
    // == m (mod 8) -> same XCD -> A fetched once/L2 (FETCH 528->130MB).
    const int m0 = (blockIdx.x & 63) * 256;   // m inner: 64 m-groups
    const int n0 = (blockIdx.x >> 6) * 128;   // n outer: 8 n-panels
    v4i acc[8][4];
    v4i zero = {0, 0, 0, 0};
#pragma unroll
    for (int i = 0; i < 8; i++)
#pragma unroll
        for (int j = 0; j < 4; j++) acc[i][j] = zero;

    // stage-2 scales decoded inline from slots (same math as old k_scales2)
    float amin = dec_f(slots[4]), amax = dec_f(slots[5]);
    float sh = fmaxf((amax - amin) / 255.0f, 1e-8f);
    float zpf = rintf(-amin / sh) - 128.0f;
    zpf = fminf(fmaxf(zpf, -128.0f), 127.0f);
    float rs = 1.0f / sh;             // one exact IEEE division per thread
    float zpm = zpf + MAGIC;          // shifted zero-point for magic rounding
    float s2 = sh * scal[3];
    int zx = (int)zpf;

    int8_mainloop_h(Hm, Bq, D_HID, m0, n0, rs, zpm, Ls, acc);

    const int tid = threadIdx.x, l = tid & 63, w = tid >> 6;
    const int lm = l & 15, lq = l >> 4;
    const int wmi = w >> 1, wni = w & 1;
#pragma unroll
    for (int j = 0; j < 4; j++) {
        int n = n0 + (wni << 6) + j * 16 + lm;
        int rsn = rsum[n];
        float bn = bias[n];
#pragma unroll
        for (int i = 0; i < 8; i++) {
            int mb = m0 + (wmi << 7) + i * 16 + lq * 4;
#pragma unroll
            for (int rg = 0; rg < 4; rg++) {
                int v = acc[i][j][rg] - zx * rsn;
                Out[(long)(mb + rg) * D_IN + n] = (float)v * s2 + bn;
            }
        }
    }
}

extern "C" void kernel_launch(void* const* d_in, const int* in_sizes, int n_in,
                              void* d_out, int out_size, void* d_ws, size_t ws_size,
                              hipStream_t stream) {
    const float* x  = (const float*)d_in[0];
    const float* W1 = (const float*)d_in[1];
    const float* b1 = (const float*)d_in[2];
    const float* W2 = (const float*)d_in[3];
    const float* b2 = (const float*)d_in[4];

    char* ws = (char*)d_ws;
    unsigned* slots    = (unsigned*)(ws + OFF_SLOTS);
    float* scal        = (float*)(ws + OFF_SCAL);
    int* iscal         = (int*)(ws + OFF_ISCAL);
    signed char* xq    = (signed char*)(ws + OFF_XQ);
    signed char* w1q   = (signed char*)(ws + OFF_W1Q);
    signed char* w2q   = (signed char*)(ws + OFF_W2Q);
    int* rs1           = (int*)(ws + OFF_RS1);
    int* rs2           = (int*)(ws + OFF_RS2);
    _Float16* h        = (_Float16*)(ws + OFF_H);

    // reduction partials: written by k_reduce_all, read by k_quant_all, dead after.
    float* pxmin = (float*)(ws + OFF_PART);         // 1024 f32
    float* pxmax = pxmin + 1024;                    // 1024 f32
    float* pw1   = pxmax + 1024;                    // 256 f32
    float* pw2   = pw1 + 256;                       // 256 f32  (10KB total)

    k_reduce_all<<<1536, 256, 0, stream>>>((const float4*)x, (const float4*)W1,
                                           (const float4*)W2, pxmin, pxmax, pw1, pw2);
    k_quant_all<<<7168, 256, 0, stream>>>((const float4*)x, (int*)xq,
                                          W1, w1q, rs1, W2, w2q, rs2,
                                          pxmin, pxmax, pw1, pw2, scal, iscal, slots);
    k_gemm1<<<(M_TOK / 256) * (D_HID / 128), 256, 0, stream>>>(xq, w1q, h, scal, iscal, rs1, b1, slots);
    k_gemm2<<<(M_TOK / 256) * (D_IN / 128), 256, 0, stream>>>(h, w2q, (float*)d_out, scal, slots, rs2, b2);
}